// Round 2
// baseline (3033.283 us; speedup 1.0000x reference)
//
#include <hip/hip_runtime.h>
#include <math.h>

#define N 64
#define LDC 68            // col-major leading dim (floats); 68 mod 32 = 4 -> column base bank
                          // advances by one 4-word group per column
#define MAX_SWEEPS 10     // with early exit; typical matrices converge in ~5-6
#define SKIP_TOL2 9e-12f  // skip rotation if gamma^2 <= tol2 * a * b  (|g| <= 3e-6 * sp*sq)

// Raw-hardware approximations (~22-bit): fine for Jacobi rotation params; final
// eigenvalues are recomputed exactly from column norms.
__device__ __forceinline__ float frcp(float x)   { return __builtin_amdgcn_rcpf(x); }
__device__ __forceinline__ float fsqrt_(float x) { return __builtin_amdgcn_sqrtf(x); }
__device__ __forceinline__ float frsq(float x)   { return __builtin_amdgcn_rsqf(x); }
__device__ __forceinline__ float flog_(float x)  { return __builtin_amdgcn_logf(x) * 0.69314718056f; }

// VALU-pipe cross-lane add via DPP.
// 0xB1 = quad_perm xor1, 0x4E = quad_perm xor2, 0x141 = row_half_mirror
// (valid 3rd step: after xor1+xor2 the value is uniform within each quad).
template <int CTRL>
__device__ __forceinline__ float dpp_add(float x) {
    int m = __builtin_amdgcn_update_dpp(0, __float_as_int(x), CTRL, 0xF, 0xF, true);
    return x + __int_as_float(m);
}

__global__ __launch_bounds__(256)
void logeig_kernel(const float* __restrict__ P, float* __restrict__ Out) {
    __shared__ float As[N * LDC];   // column-major: As[c*LDC + i] = elem (row i, col c)
    __shared__ float nrm[N];        // running ||col||^2 (Gram diagonal)
    __shared__ float lw[N];         // log(lambda)/lambda
    __shared__ int ncv[2];          // double-buffered "a rotation happened" flag

    const int t = threadIdx.x;
    const int bid = blockIdx.x;
    const float* A0 = P + (size_t)bid * (N * N);
    float* O = Out + (size_t)bid * (N * N);

    // ---- Load P. Symmetric, so column c (col-major) = row c of P: coalesced.
    {
        const float4* A4 = (const float4*)A0;
        #pragma unroll
        for (int kk = 0; kk < 4; ++kk) {
            int f = t + kk * 256;           // float4 index in [0,1024)
            float4 v = A4[f];
            int e = f << 2;
            int r = e >> 6;                 // row of P = dest column
            int i = e & 63;
            *(float4*)&As[r * LDC + i] = v;
        }
    }
    __syncthreads();

    // ---- Cholesky P = L L^T, in place, lower triangle, 2 barriers per step.
    for (int k = 0; k < N; ++k) {
        float dval = fmaxf(As[k * LDC + k], 1e-20f);  // broadcast read (all threads)
        float dinv = frsq(dval);
        for (int i = k + 1 + t; i < N; i += 256) As[k * LDC + i] *= dinv;
        if (t == 0) As[k * LDC + k] = dval * dinv;    // = sqrt(dval)
        __syncthreads();
        // trailing update: A[i][j] -= L[i][k]*L[j][k], j>k, i>=j
        for (int j = k + 1 + (t >> 3); j < N; j += 32) {
            float ljk = As[k * LDC + j];
            for (int i = j + (t & 7); i < N; i += 8)
                As[j * LDC + i] = fmaf(-As[k * LDC + i], ljk, As[j * LDC + i]);
        }
        __syncthreads();
    }

    // ---- zero strict upper triangle (still holds P entries), init column norms
    for (int f = t; f < N * N; f += 256) {
        int c = f >> 6, i = f & 63;
        if (i < c) As[c * LDC + i] = 0.f;
    }
    if (t == 0) { ncv[0] = 0; ncv[1] = 0; }
    __syncthreads();
    if (t < N) {
        float s = 0.f;
        const float* cc = &As[t * LDC];
        for (int i = 0; i < N; ++i) { float x = cc[i]; s = fmaf(x, x, s); }
        nrm[t] = s;
    }
    __syncthreads();

    // ---- One-sided Jacobi on the columns of L.
    // Pair kp handled by 8 lanes (g = t&7). Lane g owns rows {4g..4g+3} and
    // {32+4g..32+4g+3}: the pair's 8 lanes cover all 32 banks exactly once per
    // b128 op, and across a wave's 8 pairs every bank-group is hit uniformly
    // -> conflict-free (the old 8g..8g+7 mapping had g/g+4 2-way everywhere).
    // Round pairs partition the 64 columns => ONE barrier per round.
    const int kp = t >> 3;    // pair index 0..31
    const int g  = t & 7;     // sub-lane within pair
    float* colg = As + 4 * g;

    // Tournament state, advanced incrementally (+1 mod 63 per round).
    int p, q;
    if (kp == 0) { p = 63; q = 0; } else { p = kp; q = 63 - kp; }
    unsigned rotated = 0;
    int conv = 0;

    for (int sweep = 0; sweep < MAX_SWEEPS && !conv; ++sweep) {
        for (int r = 0; r < 63; ++r) {
            float* cp = colg + p * LDC;
            float* cq = colg + q * LDC;
            float4 ap0 = *(float4*)cp;
            float4 ap1 = *(float4*)(cp + 32);
            float4 aq0 = *(float4*)cq;
            float4 aq1 = *(float4*)(cq + 32);
            float a = nrm[p], b = nrm[q];
            // gamma = col_p . col_q  (partial over my 8 rows, then 8-lane DPP reduce)
            float gd = ap0.x * aq0.x;
            gd = fmaf(ap0.y, aq0.y, gd);
            gd = fmaf(ap0.z, aq0.z, gd);
            gd = fmaf(ap0.w, aq0.w, gd);
            gd = fmaf(ap1.x, aq1.x, gd);
            gd = fmaf(ap1.y, aq1.y, gd);
            gd = fmaf(ap1.z, aq1.z, gd);
            gd = fmaf(ap1.w, aq1.w, gd);
            gd = dpp_add<0xB1>(gd);
            gd = dpp_add<0x4E>(gd);
            gd = dpp_add<0x141>(gd);
            if (gd * gd > SKIP_TOL2 * a * b) {
                // Jacobi rotation zeroing off-diag of Gram 2x2 [[a,g],[g,b]]
                float tau = (b - a) * 0.5f * frcp(gd);
                float tt = frcp(fabsf(tau) + fsqrt_(fmaf(tau, tau, 1.f)));
                if (tau < 0.f) tt = -tt;
                float c = frsq(fmaf(tt, tt, 1.f));
                float s = tt * c;
                float4 np0, np1, nq0, nq1;
                np0.x = c * ap0.x - s * aq0.x;  nq0.x = s * ap0.x + c * aq0.x;
                np0.y = c * ap0.y - s * aq0.y;  nq0.y = s * ap0.y + c * aq0.y;
                np0.z = c * ap0.z - s * aq0.z;  nq0.z = s * ap0.z + c * aq0.z;
                np0.w = c * ap0.w - s * aq0.w;  nq0.w = s * ap0.w + c * aq0.w;
                np1.x = c * ap1.x - s * aq1.x;  nq1.x = s * ap1.x + c * aq1.x;
                np1.y = c * ap1.y - s * aq1.y;  nq1.y = s * ap1.y + c * aq1.y;
                np1.z = c * ap1.z - s * aq1.z;  nq1.z = s * ap1.z + c * aq1.z;
                np1.w = c * ap1.w - s * aq1.w;  nq1.w = s * ap1.w + c * aq1.w;
                *(float4*)cp = np0;
                *(float4*)(cp + 32) = np1;
                *(float4*)cq = nq0;
                *(float4*)(cq + 32) = nq1;
                if (g == 0) {
                    // exact update identities: a' = a - t*g, b' = b + t*g
                    nrm[p] = a - tt * gd;
                    nrm[q] = b + tt * gd;
                }
                rotated = 1;
            }
            __syncthreads();
            // advance tournament: p,q increment mod 63 (p pinned at 63 for kp==0)
            q = (q == 62) ? 0 : q + 1;
            if (kp) p = (p == 62) ? 0 : p + 1;
        }
        // sweep-end convergence check (double-buffered flag, one extra barrier)
        if (rotated) ncv[sweep & 1] = 1;
        if (t == 0) ncv[(sweep & 1) ^ 1] = 0;
        rotated = 0;
        __syncthreads();
        conv = (ncv[sweep & 1] == 0);
    }

    // ---- eigen coefficients: column k = sigma_k * u_k, lambda = ||col||^2 (exact recompute)
    if (t < N) {
        float s = 0.f;
        const float* cc = &As[t * LDC];
        for (int i = 0; i < N; ++i) { float x = cc[i]; s = fmaf(x, x, s); }
        s = fmaxf(s, 1e-30f);
        lw[t] = flog_(s) * frcp(s);   // X = sum_k (log l / l) c_k c_k^T
    }
    __syncthreads();

    // ---- X = sum_k lw[k] * c_k c_k^T ; 4x4 output tile per thread
    {
        int ti = t >> 4;
        int tj = t & 15;
        float acc[4][4];
        #pragma unroll
        for (int a2 = 0; a2 < 4; ++a2)
            #pragma unroll
            for (int b2 = 0; b2 < 4; ++b2) acc[a2][b2] = 0.f;

        for (int k = 0; k < N; ++k) {
            float w = lw[k];
            float4 ui = *(const float4*)&As[k * LDC + 4 * ti];
            float4 uj = *(const float4*)&As[k * LDC + 4 * tj];
            uj.x *= w; uj.y *= w; uj.z *= w; uj.w *= w;
            float ua[4] = {ui.x, ui.y, ui.z, ui.w};
            float ub[4] = {uj.x, uj.y, uj.z, uj.w};
            #pragma unroll
            for (int a2 = 0; a2 < 4; ++a2)
                #pragma unroll
                for (int b2 = 0; b2 < 4; ++b2)
                    acc[a2][b2] = fmaf(ua[a2], ub[b2], acc[a2][b2]);
        }
        #pragma unroll
        for (int a2 = 0; a2 < 4; ++a2) {
            float4 vout = make_float4(acc[a2][0], acc[a2][1], acc[a2][2], acc[a2][3]);
            ((float4*)O)[(4 * ti + a2) * 16 + tj] = vout;
        }
    }
}

extern "C" void kernel_launch(void* const* d_in, const int* in_sizes, int n_in,
                              void* d_out, int out_size, void* d_ws, size_t ws_size,
                              hipStream_t stream) {
    const float* P = (const float*)d_in[0];
    float* Out = (float*)d_out;
    int nmat = in_sizes[0] / (N * N);    // 8192
    logeig_kernel<<<dim3(nmat), dim3(256), 0, stream>>>(P, Out);
}